// Round 1
// baseline (675.138 us; speedup 1.0000x reference)
//
#include <hip/hip_runtime.h>
#include <math.h>

#define DH 512
#define CC 64
#define NB 2048
#define SCALE 0.044194173824159216f   // 1/sqrt(512)

// ---------------- wave helpers ----------------
__device__ __forceinline__ float wsum(float v) {
#pragma unroll
  for (int off = 32; off; off >>= 1) v += __shfl_xor(v, off, 64);
  return v;
}
__device__ __forceinline__ float wmaxf(float v) {
#pragma unroll
  for (int off = 32; off; off >>= 1) v = fmaxf(v, __shfl_xor(v, off, 64));
  return v;
}

// ---------------- bool-layout detect + need table ----------------
// double may arrive as uint8 (1B/elem), int32 (4B), or float32 (4B). Detect from
// byte pattern: widened layouts have zeros at i%4!=0 except float32's 0x3f/0x80.
__global__ void need_kernel(const unsigned char* __restrict__ dbl,
                            int* __restrict__ need) {
  __shared__ int flagNZ, flagFP;
  const int t = threadIdx.x;
  if (t == 0) { flagNZ = 0; flagFP = 0; }
  __syncthreads();
  int nz = 0, fp = 0;
  for (int i = t; i < NB; i += 256) {
    if (i & 3) {
      unsigned char v = dbl[i];
      nz |= (v != 0);
      fp |= (v == 0x3f) | (v == 0x80);
    }
  }
  if (nz) atomicOr(&flagNZ, 1);
  if (fp) atomicOr(&flagFP, 1);
  __syncthreads();
  const int isFP = flagFP, isByte = flagNZ && !flagFP;
  for (int i = t; i < NB; i += 256) {
    int v;
    if (isFP)        v = (((const float*)dbl)[i] != 0.0f);
    else if (isByte) v = (dbl[i] != 0);
    else             v = (((const int*)dbl)[i] != 0);
    need[i] = v ? 2 : 1;
  }
}

// ---------------- fp32 tiled GEMMs (64x64 tile, 4x4 microtile) ----------------
#define BM 64
#define BN 64
#define BK 16

// C[M,512] = sum_k A[k*lda + m] * B[k*512 + n]   (both operands read "k-major")
__global__ __launch_bounds__(256) void gemm_tn(const float* __restrict__ A, int lda,
                                               const float* __restrict__ B,
                                               float* __restrict__ C, int K) {
  __shared__ float As[BK][BM];
  __shared__ float Bs[BK][BN];
  const int t = threadIdx.x;
  const int tx = t & 15, ty = t >> 4;
  const int m0 = blockIdx.x * BM, n0 = blockIdx.y * BN;
  const int srow = t >> 4, scol = (t & 15) << 2;
  float acc[4][4] = {};
  for (int k0 = 0; k0 < K; k0 += BK) {
    *(float4*)&As[srow][scol] = *(const float4*)&A[(size_t)(k0 + srow) * lda + m0 + scol];
    *(float4*)&Bs[srow][scol] = *(const float4*)&B[(size_t)(k0 + srow) * DH + n0 + scol];
    __syncthreads();
#pragma unroll
    for (int k = 0; k < BK; ++k) {
      float4 a = *(float4*)&As[k][ty << 2];
      float4 b = *(float4*)&Bs[k][tx << 2];
      float av[4] = {a.x, a.y, a.z, a.w};
      float bv[4] = {b.x, b.y, b.z, b.w};
#pragma unroll
      for (int i = 0; i < 4; ++i)
#pragma unroll
        for (int j = 0; j < 4; ++j) acc[i][j] = fmaf(av[i], bv[j], acc[i][j]);
    }
    __syncthreads();
  }
#pragma unroll
  for (int i = 0; i < 4; ++i) {
    float4 o = {acc[i][0], acc[i][1], acc[i][2], acc[i][3]};
    *(float4*)&C[(size_t)(m0 + (ty << 2) + i) * DH + n0 + (tx << 2)] = o;
  }
}

// C[M,512] = sum_k ctx[m,k] * B[k*512 + n]; ctx is 3 segments of row-length 512
// (pass the same pointer 3x for a plain [M,512] A with K=512).
__global__ __launch_bounds__(256) void gemm_nn(const float* __restrict__ A0,
                                               const float* __restrict__ A1,
                                               const float* __restrict__ A2,
                                               const float* __restrict__ B,
                                               float* __restrict__ C, int K) {
  __shared__ float As[BK][BM];
  __shared__ float Bs[BK][BN];
  const int t = threadIdx.x;
  const int tx = t & 15, ty = t >> 4;
  const int m0 = blockIdx.x * BM, n0 = blockIdx.y * BN;
  const int srowB = t >> 4, scolB = (t & 15) << 2;
  const int am = t >> 2, akq = (t & 3) << 2;
  float acc[4][4] = {};
  for (int k0 = 0; k0 < K; k0 += BK) {
    const float* base = (k0 < 512) ? A0 : ((k0 < 1024) ? A1 : A2);
    const int kk = k0 & 511;
    float4 av4 = *(const float4*)&base[(size_t)(m0 + am) * 512 + kk + akq];
    As[akq + 0][am] = av4.x;
    As[akq + 1][am] = av4.y;
    As[akq + 2][am] = av4.z;
    As[akq + 3][am] = av4.w;
    *(float4*)&Bs[srowB][scolB] = *(const float4*)&B[(size_t)(k0 + srowB) * DH + n0 + scolB];
    __syncthreads();
#pragma unroll
    for (int k = 0; k < BK; ++k) {
      float4 a = *(float4*)&As[k][ty << 2];
      float4 b = *(float4*)&Bs[k][tx << 2];
      float av[4] = {a.x, a.y, a.z, a.w};
      float bv[4] = {b.x, b.y, b.z, b.w};
#pragma unroll
      for (int i = 0; i < 4; ++i)
#pragma unroll
        for (int j = 0; j < 4; ++j) acc[i][j] = fmaf(av[i], bv[j], acc[i][j]);
    }
    __syncthreads();
  }
#pragma unroll
  for (int i = 0; i < 4; ++i) {
    float4 o = {acc[i][0], acc[i][1], acc[i][2], acc[i][3]};
    *(float4*)&C[(size_t)(m0 + (ty << 2) + i) * DH + n0 + (tx << 2)] = o;
  }
}

// ---------------- pass 1: logits -> softmax -> Gw (one block per b) ----------------
__global__ __launch_bounds__(256) void pass1_kernel(const float* __restrict__ HtC,
                                                    const int* __restrict__ caps,
                                                    const int* __restrict__ dists,
                                                    const float* __restrict__ Qk,
                                                    const float* __restrict__ cap_emb,
                                                    const float* __restrict__ dist_emb,
                                                    float* __restrict__ Gw) {
  const int b = blockIdx.x;
  const int t = threadIdx.x;
  const int wv = t >> 6, ln = t & 63;
  __shared__ float qk[DH];
  __shared__ float capQ[11], distQ[3];
  __shared__ float capw[11], distw[3];
  __shared__ float logits[CC];
  __shared__ float wts[CC];
  if (t < 11) capw[t] = 0.f;
  if (t < 3) distw[t] = 0.f;
  qk[t] = Qk[(size_t)b * DH + t];
  qk[t + 256] = Qk[(size_t)b * DH + 256 + t];
  __syncthreads();
  // embedding-vector dots with Qk[b]
#pragma unroll
  for (int r = 0; r < 3; ++r) {
    int v = wv + (r << 2);
    if (v < 11) {
      float s = 0.f;
#pragma unroll
      for (int j = 0; j < 8; ++j) s = fmaf(cap_emb[v * DH + ln + (j << 6)], qk[ln + (j << 6)], s);
      s = wsum(s);
      if (ln == 0) capQ[v] = s;
    }
  }
  if (wv < 3) {
    float s = 0.f;
#pragma unroll
    for (int j = 0; j < 8; ++j) s = fmaf(dist_emb[wv * DH + ln + (j << 6)], qk[ln + (j << 6)], s);
    s = wsum(s);
    if (ln == 0) distQ[wv] = s;
  }
  __syncthreads();
  const float4* qk4 = (const float4*)qk;
  float4 q1 = qk4[ln];
  float4 q2 = qk4[64 + ln];
  const float* hb = HtC + (size_t)b * CC * DH;
#pragma unroll 4
  for (int i = 0; i < 16; ++i) {
    int c = (wv << 4) + i;
    const float4* h4 = (const float4*)(hb + (size_t)c * DH);
    float4 h1 = h4[ln];
    float4 h2 = h4[64 + ln];
    float s = h1.x * q1.x + h1.y * q1.y + h1.z * q1.z + h1.w * q1.w +
              h2.x * q2.x + h2.y * q2.y + h2.z * q2.z + h2.w * q2.w;
    s = wsum(s);
    if (ln == 0)
      logits[c] = SCALE * (s + capQ[caps[b * CC + c]] + distQ[dists[b * CC + c]]);
  }
  __syncthreads();
  if (t < CC) {
    float x = logits[t];
    float m = wmaxf(x);
    float e = __expf(x - m);
    float ssum = wsum(e);
    float w = e / ssum;
    wts[t] = w;
    atomicAdd(&capw[caps[b * CC + t]], w);
    atomicAdd(&distw[dists[b * CC + t]], w);
  }
  __syncthreads();
#pragma unroll
  for (int dd = 0; dd < 2; ++dd) {
    int d = t + (dd << 8);
    float g = 0.f;
#pragma unroll 8
    for (int c = 0; c < CC; ++c) g = fmaf(wts[c], hb[(size_t)c * DH + d], g);
#pragma unroll
    for (int v = 0; v < 11; ++v) g = fmaf(capw[v], cap_emb[v * DH + d], g);
#pragma unroll
    for (int v = 0; v < 3; ++v) g = fmaf(distw[v], dist_emb[v * DH + d], g);
    Gw[(size_t)b * DH + d] = g;
  }
}

// ---------------- pass 2: u -> mask -> softmax -> out ----------------
__global__ __launch_bounds__(256) void pass2_kernel(const float* __restrict__ HtC,
                                                    const int* __restrict__ caps,
                                                    const int* __restrict__ dists,
                                                    const float* __restrict__ gkv,
                                                    const float* __restrict__ cap_emb,
                                                    const float* __restrict__ dist_emb,
                                                    const int* __restrict__ need,
                                                    float* __restrict__ out) {
  const int b = blockIdx.x;
  const int t = threadIdx.x;
  const int wv = t >> 6, ln = t & 63;
  __shared__ float gk[DH];
  __shared__ float capG[11], distG[3];
  __shared__ float ulog[CC];
  gk[t] = gkv[(size_t)b * DH + t];
  gk[t + 256] = gkv[(size_t)b * DH + 256 + t];
  __syncthreads();
#pragma unroll
  for (int r = 0; r < 3; ++r) {
    int v = wv + (r << 2);
    if (v < 11) {
      float s = 0.f;
#pragma unroll
      for (int j = 0; j < 8; ++j) s = fmaf(cap_emb[v * DH + ln + (j << 6)], gk[ln + (j << 6)], s);
      s = wsum(s);
      if (ln == 0) capG[v] = s;
    }
  }
  if (wv < 3) {
    float s = 0.f;
#pragma unroll
    for (int j = 0; j < 8; ++j) s = fmaf(dist_emb[wv * DH + ln + (j << 6)], gk[ln + (j << 6)], s);
    s = wsum(s);
    if (ln == 0) distG[wv] = s;
  }
  __syncthreads();
  const float4* gk4 = (const float4*)gk;
  float4 q1 = gk4[ln];
  float4 q2 = gk4[64 + ln];
  const float* hb = HtC + (size_t)b * CC * DH;
#pragma unroll 4
  for (int i = 0; i < 16; ++i) {
    int c = (wv << 4) + i;
    const float4* h4 = (const float4*)(hb + (size_t)c * DH);
    float4 h1 = h4[ln];
    float4 h2 = h4[64 + ln];
    float s = h1.x * q1.x + h1.y * q1.y + h1.z * q1.z + h1.w * q1.w +
              h2.x * q2.x + h2.y * q2.y + h2.z * q2.z + h2.w * q2.w;
    s = wsum(s);
    if (ln == 0)
      ulog[c] = SCALE * (s + capG[caps[b * CC + c]] + distG[dists[b * CC + c]]);
  }
  __syncthreads();
  if (t < CC) {
    int nb = need[b];
    float x = ulog[t];
    if (caps[b * CC + t] < nb) x = -INFINITY;
    float m = wmaxf(x);
    float e = __expf(x - m);   // exp(-inf - m) = 0
    float ssum = wsum(e);
    out[(size_t)b * CC + t] = e / ssum;
  }
}

// ---------------- launch ----------------
extern "C" void kernel_launch(void* const* d_in, const int* in_sizes, int n_in,
                              void* d_out, int out_size, void* d_ws, size_t ws_size,
                              hipStream_t stream) {
  const float* HtC      = (const float*)d_in[0];
  const int* caps       = (const int*)d_in[1];
  const int* dists      = (const int*)d_in[2];
  const float* H_X      = (const float*)d_in[3];
  const float* Ht_S     = (const float*)d_in[4];
  const float* Eq_Q     = (const float*)d_in[5];
  const unsigned char* dbl = (const unsigned char*)d_in[6];
  const float* cap_emb  = (const float*)d_in[7];
  const float* dist_emb = (const float*)d_in[8];
  const float* W_q      = (const float*)d_in[9];
  const float* W_k      = (const float*)d_in[10];
  const float* W_v      = (const float*)d_in[11];
  float* out = (float*)d_out;

  float* ws    = (float*)d_ws;
  float* wsA   = ws;                       // [1536,512]  A = W_q^T @ W_k
  float* wsM   = wsA + 1536 * 512;         // [512,512]   M = W_v^T @ W_k
  float* wsQk  = wsM + 512 * 512;          // [2048,512]  Qk = ctx @ A
  float* wsGw  = wsQk + 2048 * 512;        // [2048,512]
  float* wsGk  = wsGw + 2048 * 512;        // [2048,512]  gk = Gw @ M
  int* wsNeed  = (int*)(wsGk + 2048 * 512);

  need_kernel<<<1, 256, 0, stream>>>(dbl, wsNeed);
  // A[j,d] = sum_e W_q[e,j] * W_k[e,d]
  gemm_tn<<<dim3(1536 / BM, 512 / BN), 256, 0, stream>>>(W_q, 3 * DH, W_k, wsA, DH);
  // M[d',d] = sum_e W_v[e,d'] * W_k[e,d]
  gemm_tn<<<dim3(512 / BM, 512 / BN), 256, 0, stream>>>(W_v, DH, W_k, wsM, DH);
  // Qk = ctx @ A  (ctx = [H_X | Ht_S | Eq_Q])
  gemm_nn<<<dim3(2048 / BM, 512 / BN), 256, 0, stream>>>(H_X, Ht_S, Eq_Q, wsA, wsQk, 3 * DH);
  pass1_kernel<<<NB, 256, 0, stream>>>(HtC, caps, dists, wsQk, cap_emb, dist_emb, wsGw);
  // gk = Gw @ M
  gemm_nn<<<dim3(2048 / BM, 512 / BN), 256, 0, stream>>>(wsGw, wsGw, wsGw, wsM, wsGk, DH);
  pass2_kernel<<<NB, 256, 0, stream>>>(HtC, caps, dists, wsGk, cap_emb, dist_emb, wsNeed, out);
}

// Round 2
// 638.090 us; speedup vs baseline: 1.0581x; 1.0581x over previous
//
#include <hip/hip_runtime.h>
#include <math.h>

#define DH 512
#define CC 64
#define NB 2048
#define SCALE 0.044194173824159216f   // 1/sqrt(512)

// ---------------- wave helpers ----------------
__device__ __forceinline__ float wsum(float v) {
#pragma unroll
  for (int off = 32; off; off >>= 1) v += __shfl_xor(v, off, 64);
  return v;
}
__device__ __forceinline__ float wmaxf(float v) {
#pragma unroll
  for (int off = 32; off; off >>= 1) v = fmaxf(v, __shfl_xor(v, off, 64));
  return v;
}

// ---------------- zero-init (ws is poisoned 0xAA before every launch) -------
__global__ void zero2_kernel(float* __restrict__ p0, float* __restrict__ p1, int n) {
  int i = blockIdx.x * blockDim.x + threadIdx.x;
  int stride = gridDim.x * blockDim.x;
  for (; i < n; i += stride) { p0[i] = 0.f; p1[i] = 0.f; }
}

// ---------------- bool-layout detect + need table ----------------
__global__ void need_kernel(const unsigned char* __restrict__ dbl,
                            int* __restrict__ need) {
  __shared__ int flagNZ, flagFP;
  const int t = threadIdx.x;
  if (t == 0) { flagNZ = 0; flagFP = 0; }
  __syncthreads();
  int nz = 0, fp = 0;
  for (int i = t; i < NB; i += 256) {
    if (i & 3) {
      unsigned char v = dbl[i];
      nz |= (v != 0);
      fp |= (v == 0x3f) | (v == 0x80);
    }
  }
  if (nz) atomicOr(&flagNZ, 1);
  if (fp) atomicOr(&flagFP, 1);
  __syncthreads();
  const int isFP = flagFP, isByte = flagNZ && !flagFP;
  for (int i = t; i < NB; i += 256) {
    int v;
    if (isFP)        v = (((const float*)dbl)[i] != 0.0f);
    else if (isByte) v = (dbl[i] != 0);
    else             v = (((const int*)dbl)[i] != 0);
    need[i] = v ? 2 : 1;
  }
}

// ============ GEMM v2: 128x64 tile, 8x4 micro, 256 thr, reg-prefetch ========
// A row-major (3 segments of 512 cols), B row-major [K,512], optional split-K
// with atomicAdd epilogue.
#define AS_STR 132   // +4 pad: transposed A-store spreads banks

__global__ __launch_bounds__(256) void gemm_nn2(const float* __restrict__ A0,
                                                const float* __restrict__ A1,
                                                const float* __restrict__ A2,
                                                const float* __restrict__ B,
                                                float* __restrict__ C,
                                                int kchunk, int use_atomic) {
  __shared__ float As[16 * AS_STR];
  __shared__ float Bs[16 * 64];
  const int t = threadIdx.x;
  const int m0 = blockIdx.x * 128, n0 = blockIdx.y * 64;
  const int kbeg = blockIdx.z * kchunk, kend = kbeg + kchunk;
  const int tx = t & 15, ty = t >> 4;
  const int ar0 = t >> 2;            // A rows: ar0 and ar0+64
  const int ak4 = (t & 3) << 2;      // A k-offset within tile
  const int bk = t >> 4, bn4 = (t & 15) << 2;

  float4 ra0, ra1, rb;
  {
    const float* base = (kbeg < 512) ? A0 : ((kbeg < 1024) ? A1 : A2);
    const int kk = kbeg & 511;
    ra0 = *(const float4*)&base[(size_t)(m0 + ar0) * 512 + kk + ak4];
    ra1 = *(const float4*)&base[(size_t)(m0 + ar0 + 64) * 512 + kk + ak4];
    rb  = *(const float4*)&B[(size_t)(kbeg + bk) * 512 + n0 + bn4];
  }
  float acc[8][4] = {};
  for (int k0 = kbeg; k0 < kend; k0 += 16) {
    __syncthreads();
    As[(ak4 + 0) * AS_STR + ar0] = ra0.x;
    As[(ak4 + 1) * AS_STR + ar0] = ra0.y;
    As[(ak4 + 2) * AS_STR + ar0] = ra0.z;
    As[(ak4 + 3) * AS_STR + ar0] = ra0.w;
    As[(ak4 + 0) * AS_STR + ar0 + 64] = ra1.x;
    As[(ak4 + 1) * AS_STR + ar0 + 64] = ra1.y;
    As[(ak4 + 2) * AS_STR + ar0 + 64] = ra1.z;
    As[(ak4 + 3) * AS_STR + ar0 + 64] = ra1.w;
    *(float4*)&Bs[bk * 64 + bn4] = rb;
    __syncthreads();
    if (k0 + 16 < kend) {
      const int kn = k0 + 16;
      const float* base = (kn < 512) ? A0 : ((kn < 1024) ? A1 : A2);
      const int kk = kn & 511;
      ra0 = *(const float4*)&base[(size_t)(m0 + ar0) * 512 + kk + ak4];
      ra1 = *(const float4*)&base[(size_t)(m0 + ar0 + 64) * 512 + kk + ak4];
      rb  = *(const float4*)&B[(size_t)(kn + bk) * 512 + n0 + bn4];
    }
#pragma unroll
    for (int k = 0; k < 16; ++k) {
      float4 a0 = *(float4*)&As[k * AS_STR + (ty << 3)];
      float4 a1 = *(float4*)&As[k * AS_STR + (ty << 3) + 4];
      float4 b  = *(float4*)&Bs[k * 64 + (tx << 2)];
      float av[8] = {a0.x, a0.y, a0.z, a0.w, a1.x, a1.y, a1.z, a1.w};
      float bv[4] = {b.x, b.y, b.z, b.w};
#pragma unroll
      for (int i = 0; i < 8; ++i)
#pragma unroll
        for (int j = 0; j < 4; ++j) acc[i][j] = fmaf(av[i], bv[j], acc[i][j]);
    }
  }
#pragma unroll
  for (int i = 0; i < 8; ++i) {
    float* cp = &C[(size_t)(m0 + (ty << 3) + i) * 512 + n0 + (tx << 2)];
    if (use_atomic) {
      atomicAdd(cp + 0, acc[i][0]);
      atomicAdd(cp + 1, acc[i][1]);
      atomicAdd(cp + 2, acc[i][2]);
      atomicAdd(cp + 3, acc[i][3]);
    } else {
      float4 o = {acc[i][0], acc[i][1], acc[i][2], acc[i][3]};
      *(float4*)cp = o;
    }
  }
}

// Combined weight-precompute GEMM (k-major A): rows 0..1535 from W_q cols
// (A = W_q^T @ W_k -> wsA), rows 1536..2047 from W_v cols (M = W_v^T @ W_k -> wsM).
__global__ __launch_bounds__(256) void gemm_tn2(const float* __restrict__ Wq,
                                                const float* __restrict__ Wv,
                                                const float* __restrict__ Wk,
                                                float* __restrict__ Aout,
                                                float* __restrict__ Mout) {
  __shared__ float As[16 * 128];
  __shared__ float Bs[16 * 64];
  const int t = threadIdx.x;
  const int m0 = blockIdx.x * 128, n0 = blockIdx.y * 64;
  const int tx = t & 15, ty = t >> 4;
  const int ak = t >> 5, am4 = (t & 31) << 2;   // A: k rows ak and ak+8, m-offset
  const int bk = t >> 4, bn4 = (t & 15) << 2;
  const bool isQ = (m0 < 1536);
  const float* Acol = isQ ? (Wq + m0) : (Wv + (m0 - 1536));
  const int lda = isQ ? 1536 : 512;
  float* Cout = isQ ? (Aout + (size_t)m0 * 512) : (Mout + (size_t)(m0 - 1536) * 512);

  float4 ra0, ra1, rb;
  ra0 = *(const float4*)&Acol[(size_t)ak * lda + am4];
  ra1 = *(const float4*)&Acol[(size_t)(ak + 8) * lda + am4];
  rb  = *(const float4*)&Wk[(size_t)bk * 512 + n0 + bn4];
  float acc[8][4] = {};
  for (int k0 = 0; k0 < 512; k0 += 16) {
    __syncthreads();
    *(float4*)&As[ak * 128 + am4] = ra0;
    *(float4*)&As[(ak + 8) * 128 + am4] = ra1;
    *(float4*)&Bs[bk * 64 + bn4] = rb;
    __syncthreads();
    if (k0 + 16 < 512) {
      const int kn = k0 + 16;
      ra0 = *(const float4*)&Acol[(size_t)(kn + ak) * lda + am4];
      ra1 = *(const float4*)&Acol[(size_t)(kn + ak + 8) * lda + am4];
      rb  = *(const float4*)&Wk[(size_t)(kn + bk) * 512 + n0 + bn4];
    }
#pragma unroll
    for (int k = 0; k < 16; ++k) {
      float4 a0 = *(float4*)&As[k * 128 + (ty << 3)];
      float4 a1 = *(float4*)&As[k * 128 + (ty << 3) + 4];
      float4 b  = *(float4*)&Bs[k * 64 + (tx << 2)];
      float av[8] = {a0.x, a0.y, a0.z, a0.w, a1.x, a1.y, a1.z, a1.w};
      float bv[4] = {b.x, b.y, b.z, b.w};
#pragma unroll
      for (int i = 0; i < 8; ++i)
#pragma unroll
        for (int j = 0; j < 4; ++j) acc[i][j] = fmaf(av[i], bv[j], acc[i][j]);
    }
  }
#pragma unroll
  for (int i = 0; i < 8; ++i) {
    float4 o = {acc[i][0], acc[i][1], acc[i][2], acc[i][3]};
    *(float4*)&Cout[(size_t)((ty << 3) + i) * 512 + n0 + (tx << 2)] = o;
  }
}

// ---------------- pass 1: logits -> softmax -> Gw (one block per b) ----------
__global__ __launch_bounds__(256) void pass1_kernel(const float* __restrict__ HtC,
                                                    const int* __restrict__ caps,
                                                    const int* __restrict__ dists,
                                                    const float* __restrict__ Qk,
                                                    const float* __restrict__ cap_emb,
                                                    const float* __restrict__ dist_emb,
                                                    float* __restrict__ Gw) {
  const int b = blockIdx.x;
  const int t = threadIdx.x;
  const int wv = t >> 6, ln = t & 63;
  __shared__ float qk[DH];
  __shared__ float capQ[11], distQ[3];
  __shared__ float capw[11], distw[3];
  __shared__ float logits[CC];
  __shared__ float wts[CC];
  if (t < 11) capw[t] = 0.f;
  if (t < 3) distw[t] = 0.f;
  qk[t] = Qk[(size_t)b * DH + t];
  qk[t + 256] = Qk[(size_t)b * DH + 256 + t];
  __syncthreads();
#pragma unroll
  for (int r = 0; r < 3; ++r) {
    int v = wv + (r << 2);
    if (v < 11) {
      float s = 0.f;
#pragma unroll
      for (int j = 0; j < 8; ++j) s = fmaf(cap_emb[v * DH + ln + (j << 6)], qk[ln + (j << 6)], s);
      s = wsum(s);
      if (ln == 0) capQ[v] = s;
    }
  }
  if (wv < 3) {
    float s = 0.f;
#pragma unroll
    for (int j = 0; j < 8; ++j) s = fmaf(dist_emb[wv * DH + ln + (j << 6)], qk[ln + (j << 6)], s);
    s = wsum(s);
    if (ln == 0) distQ[wv] = s;
  }
  __syncthreads();
  const float4* qk4 = (const float4*)qk;
  float4 q1 = qk4[ln];
  float4 q2 = qk4[64 + ln];
  const float* hb = HtC + (size_t)b * CC * DH;
#pragma unroll 4
  for (int i = 0; i < 16; ++i) {
    int c = (wv << 4) + i;
    const float4* h4 = (const float4*)(hb + (size_t)c * DH);
    float4 h1 = h4[ln];
    float4 h2 = h4[64 + ln];
    float s = h1.x * q1.x + h1.y * q1.y + h1.z * q1.z + h1.w * q1.w +
              h2.x * q2.x + h2.y * q2.y + h2.z * q2.z + h2.w * q2.w;
    s = wsum(s);
    if (ln == 0)
      logits[c] = SCALE * (s + capQ[caps[b * CC + c]] + distQ[dists[b * CC + c]]);
  }
  __syncthreads();
  if (t < CC) {
    float x = logits[t];
    float m = wmaxf(x);
    float e = __expf(x - m);
    float ssum = wsum(e);
    float w = e / ssum;
    wts[t] = w;
    atomicAdd(&capw[caps[b * CC + t]], w);
    atomicAdd(&distw[dists[b * CC + t]], w);
  }
  __syncthreads();
#pragma unroll
  for (int dd = 0; dd < 2; ++dd) {
    int d = t + (dd << 8);
    float g = 0.f;
#pragma unroll 8
    for (int c = 0; c < CC; ++c) g = fmaf(wts[c], hb[(size_t)c * DH + d], g);
#pragma unroll
    for (int v = 0; v < 11; ++v) g = fmaf(capw[v], cap_emb[v * DH + d], g);
#pragma unroll
    for (int v = 0; v < 3; ++v) g = fmaf(distw[v], dist_emb[v * DH + d], g);
    Gw[(size_t)b * DH + d] = g;
  }
}

// ---------------- pass 2: u -> mask -> softmax -> out ----------------
__global__ __launch_bounds__(256) void pass2_kernel(const float* __restrict__ HtC,
                                                    const int* __restrict__ caps,
                                                    const int* __restrict__ dists,
                                                    const float* __restrict__ gkv,
                                                    const float* __restrict__ cap_emb,
                                                    const float* __restrict__ dist_emb,
                                                    const int* __restrict__ need,
                                                    float* __restrict__ out) {
  const int b = blockIdx.x;
  const int t = threadIdx.x;
  const int wv = t >> 6, ln = t & 63;
  __shared__ float gk[DH];
  __shared__ float capG[11], distG[3];
  __shared__ float ulog[CC];
  gk[t] = gkv[(size_t)b * DH + t];
  gk[t + 256] = gkv[(size_t)b * DH + 256 + t];
  __syncthreads();
#pragma unroll
  for (int r = 0; r < 3; ++r) {
    int v = wv + (r << 2);
    if (v < 11) {
      float s = 0.f;
#pragma unroll
      for (int j = 0; j < 8; ++j) s = fmaf(cap_emb[v * DH + ln + (j << 6)], gk[ln + (j << 6)], s);
      s = wsum(s);
      if (ln == 0) capG[v] = s;
    }
  }
  if (wv < 3) {
    float s = 0.f;
#pragma unroll
    for (int j = 0; j < 8; ++j) s = fmaf(dist_emb[wv * DH + ln + (j << 6)], gk[ln + (j << 6)], s);
    s = wsum(s);
    if (ln == 0) distG[wv] = s;
  }
  __syncthreads();
  const float4* gk4 = (const float4*)gk;
  float4 q1 = gk4[ln];
  float4 q2 = gk4[64 + ln];
  const float* hb = HtC + (size_t)b * CC * DH;
#pragma unroll 4
  for (int i = 0; i < 16; ++i) {
    int c = (wv << 4) + i;
    const float4* h4 = (const float4*)(hb + (size_t)c * DH);
    float4 h1 = h4[ln];
    float4 h2 = h4[64 + ln];
    float s = h1.x * q1.x + h1.y * q1.y + h1.z * q1.z + h1.w * q1.w +
              h2.x * q2.x + h2.y * q2.y + h2.z * q2.z + h2.w * q2.w;
    s = wsum(s);
    if (ln == 0)
      ulog[c] = SCALE * (s + capG[caps[b * CC + c]] + distG[dists[b * CC + c]]);
  }
  __syncthreads();
  if (t < CC) {
    int nb = need[b];
    float x = ulog[t];
    if (caps[b * CC + t] < nb) x = -INFINITY;
    float m = wmaxf(x);
    float e = __expf(x - m);
    float ssum = wsum(e);
    out[(size_t)b * CC + t] = e / ssum;
  }
}

// ---------------- launch ----------------
extern "C" void kernel_launch(void* const* d_in, const int* in_sizes, int n_in,
                              void* d_out, int out_size, void* d_ws, size_t ws_size,
                              hipStream_t stream) {
  const float* HtC      = (const float*)d_in[0];
  const int* caps       = (const int*)d_in[1];
  const int* dists      = (const int*)d_in[2];
  const float* H_X      = (const float*)d_in[3];
  const float* Ht_S     = (const float*)d_in[4];
  const float* Eq_Q     = (const float*)d_in[5];
  const unsigned char* dbl = (const unsigned char*)d_in[6];
  const float* cap_emb  = (const float*)d_in[7];
  const float* dist_emb = (const float*)d_in[8];
  const float* W_q      = (const float*)d_in[9];
  const float* W_k      = (const float*)d_in[10];
  const float* W_v      = (const float*)d_in[11];
  float* out = (float*)d_out;

  float* ws    = (float*)d_ws;
  float* wsA   = ws;                       // [1536,512]  A = W_q^T @ W_k
  float* wsM   = wsA + 1536 * 512;         // [512,512]   M = W_v^T @ W_k
  float* wsQk  = wsM + 512 * 512;          // [2048,512]  Qk = ctx @ A
  float* wsGw  = wsQk + 2048 * 512;        // [2048,512]
  float* wsGk  = wsGw + 2048 * 512;        // [2048,512]  gk = Gw @ M
  int* wsNeed  = (int*)(wsGk + 2048 * 512);

  // split-K GEMMs accumulate atomically -> zero their outputs first
  zero2_kernel<<<512, 256, 0, stream>>>(wsQk, wsGk, 2048 * 512);
  need_kernel<<<1, 256, 0, stream>>>(dbl, wsNeed);
  // combined: wsA = W_q^T @ W_k (rows 0..1535), wsM = W_v^T @ W_k (rows 1536..2047)
  gemm_tn2<<<dim3(16, 8), 256, 0, stream>>>(W_q, W_v, W_k, wsA, wsM);
  // Qk = ctx @ wsA, K=1536, split-K=4 (chunk 384)
  gemm_nn2<<<dim3(16, 8, 4), 256, 0, stream>>>(H_X, Ht_S, Eq_Q, wsA, wsQk, 384, 1);
  pass1_kernel<<<NB, 256, 0, stream>>>(HtC, caps, dists, wsQk, cap_emb, dist_emb, wsGw);
  // gk = Gw @ wsM, K=512, split-K=2 (chunk 256)
  gemm_nn2<<<dim3(16, 8, 2), 256, 0, stream>>>(wsGw, wsGw, wsGw, wsM, wsGk, 256, 1);
  pass2_kernel<<<NB, 256, 0, stream>>>(HtC, caps, dists, wsGk, cap_emb, dist_emb, wsNeed, out);
}

// Round 3
// 530.199 us; speedup vs baseline: 1.2734x; 1.2035x over previous
//
#include <hip/hip_runtime.h>
#include <math.h>

#define DH 512
#define CC 64
#define NB 2048
#define SCALE 0.044194173824159216f   // 1/sqrt(512)

// ---------------- wave helpers ----------------
__device__ __forceinline__ float wsum(float v) {
#pragma unroll
  for (int off = 32; off; off >>= 1) v += __shfl_xor(v, off, 64);
  return v;
}

// ============================================================================
// pre_kernel: blocks 0..255 compute wsA = W_q^T @ W_k (rows 0..1535) and
// wsM = W_v^T @ W_k (rows 1536..2047) with 64x64 tiles; block 256 does the
// bool-layout detection for `double` -> need[b] in {1,2}.
// ============================================================================
__global__ __launch_bounds__(128) void pre_kernel(const float* __restrict__ Wq,
                                                  const float* __restrict__ Wv,
                                                  const float* __restrict__ Wk,
                                                  float* __restrict__ Aout,
                                                  float* __restrict__ Mout,
                                                  const unsigned char* __restrict__ dbl,
                                                  int* __restrict__ need) {
  const int bx = blockIdx.x;
  const int t = threadIdx.x;
  if (bx == 256) {
    // ---- need detection ----
    __shared__ int flagNZ, flagFP;
    if (t == 0) { flagNZ = 0; flagFP = 0; }
    __syncthreads();
    int nz = 0, fp = 0;
    for (int i = t; i < NB; i += 128) {
      if (i & 3) {
        unsigned char v = dbl[i];
        nz |= (v != 0);
        fp |= (v == 0x3f) | (v == 0x80);
      }
    }
    if (nz) atomicOr(&flagNZ, 1);
    if (fp) atomicOr(&flagFP, 1);
    __syncthreads();
    const int isFP = flagFP, isByte = flagNZ && !flagFP;
    for (int i = t; i < NB; i += 128) {
      int v;
      if (isFP)        v = (((const float*)dbl)[i] != 0.0f);
      else if (isByte) v = (dbl[i] != 0);
      else             v = (((const int*)dbl)[i] != 0);
      need[i] = v ? 2 : 1;
    }
    return;
  }
  // ---- 64x64 TN GEMM tile ----
  __shared__ float As[16][64];
  __shared__ float Bs[16][64];
  const int mt = bx >> 3, nt = bx & 7;
  const int m0 = mt * 64, n0 = nt * 64;
  const bool isQ = (m0 < 1536);
  const float* Acol = isQ ? (Wq + m0) : (Wv + (m0 - 1536));
  const int lda = isQ ? 1536 : 512;
  float* Cout = isQ ? (Aout + (size_t)m0 * 512) : (Mout + (size_t)(m0 - 1536) * 512);
  const int lr = t >> 3;            // staging row 0..15
  const int lc = (t & 7) << 3;      // staging col 0,8,...,56
  const int tx = t & 15, ty = t >> 4;  // micro: n 4-wide, m 8-wide

  float4 ra0, ra1, rb0, rb1;
  ra0 = *(const float4*)&Acol[(size_t)lr * lda + lc];
  ra1 = *(const float4*)&Acol[(size_t)lr * lda + lc + 4];
  rb0 = *(const float4*)&Wk[(size_t)lr * 512 + n0 + lc];
  rb1 = *(const float4*)&Wk[(size_t)lr * 512 + n0 + lc + 4];
  float acc[8][4] = {};
  for (int k0 = 0; k0 < 512; k0 += 16) {
    __syncthreads();
    *(float4*)&As[lr][lc] = ra0;
    *(float4*)&As[lr][lc + 4] = ra1;
    *(float4*)&Bs[lr][lc] = rb0;
    *(float4*)&Bs[lr][lc + 4] = rb1;
    __syncthreads();
    if (k0 + 16 < 512) {
      const int kn = k0 + 16 + lr;
      ra0 = *(const float4*)&Acol[(size_t)kn * lda + lc];
      ra1 = *(const float4*)&Acol[(size_t)kn * lda + lc + 4];
      rb0 = *(const float4*)&Wk[(size_t)kn * 512 + n0 + lc];
      rb1 = *(const float4*)&Wk[(size_t)kn * 512 + n0 + lc + 4];
    }
#pragma unroll
    for (int k = 0; k < 16; ++k) {
      float4 a0 = *(float4*)&As[k][ty << 3];
      float4 a1 = *(float4*)&As[k][(ty << 3) + 4];
      float4 b  = *(float4*)&Bs[k][tx << 2];
      float av[8] = {a0.x, a0.y, a0.z, a0.w, a1.x, a1.y, a1.z, a1.w};
      float bv[4] = {b.x, b.y, b.z, b.w};
#pragma unroll
      for (int i = 0; i < 8; ++i)
#pragma unroll
        for (int j = 0; j < 4; ++j) acc[i][j] = fmaf(av[i], bv[j], acc[i][j]);
    }
  }
#pragma unroll
  for (int i = 0; i < 8; ++i) {
    float4 o = {acc[i][0], acc[i][1], acc[i][2], acc[i][3]};
    *(float4*)&Cout[(size_t)((ty << 3) + i) * 512 + n0 + (tx << 2)] = o;
  }
}

// ============================================================================
// gemm_nn2p: 128x64 tile, 8x4 micro, reg-prefetch, split-K to PARTIAL buffers
// Cp[z][2048][512] (no atomics; consumer sums). A is 3 row-major segments.
// ============================================================================
#define AS_STR 132

__global__ __launch_bounds__(256) void gemm_nn2p(const float* __restrict__ A0,
                                                 const float* __restrict__ A1,
                                                 const float* __restrict__ A2,
                                                 const float* __restrict__ B,
                                                 float* __restrict__ Cp,
                                                 int kchunk) {
  __shared__ float As[16 * AS_STR];
  __shared__ float Bs[16 * 64];
  const int t = threadIdx.x;
  const int m0 = blockIdx.x * 128, n0 = blockIdx.y * 64;
  const int kbeg = blockIdx.z * kchunk, kend = kbeg + kchunk;
  float* C = Cp + (size_t)blockIdx.z * (NB * DH);
  const int tx = t & 15, ty = t >> 4;
  const int ar0 = t >> 2;
  const int ak4 = (t & 3) << 2;
  const int bk = t >> 4, bn4 = (t & 15) << 2;

  float4 ra0, ra1, rb;
  {
    const float* base = (kbeg < 512) ? A0 : ((kbeg < 1024) ? A1 : A2);
    const int kk = kbeg & 511;
    ra0 = *(const float4*)&base[(size_t)(m0 + ar0) * 512 + kk + ak4];
    ra1 = *(const float4*)&base[(size_t)(m0 + ar0 + 64) * 512 + kk + ak4];
    rb  = *(const float4*)&B[(size_t)(kbeg + bk) * 512 + n0 + bn4];
  }
  float acc[8][4] = {};
  for (int k0 = kbeg; k0 < kend; k0 += 16) {
    __syncthreads();
    As[(ak4 + 0) * AS_STR + ar0] = ra0.x;
    As[(ak4 + 1) * AS_STR + ar0] = ra0.y;
    As[(ak4 + 2) * AS_STR + ar0] = ra0.z;
    As[(ak4 + 3) * AS_STR + ar0] = ra0.w;
    As[(ak4 + 0) * AS_STR + ar0 + 64] = ra1.x;
    As[(ak4 + 1) * AS_STR + ar0 + 64] = ra1.y;
    As[(ak4 + 2) * AS_STR + ar0 + 64] = ra1.z;
    As[(ak4 + 3) * AS_STR + ar0 + 64] = ra1.w;
    *(float4*)&Bs[bk * 64 + bn4] = rb;
    __syncthreads();
    if (k0 + 16 < kend) {
      const int kn = k0 + 16;
      const float* base = (kn < 512) ? A0 : ((kn < 1024) ? A1 : A2);
      const int kk = kn & 511;
      ra0 = *(const float4*)&base[(size_t)(m0 + ar0) * 512 + kk + ak4];
      ra1 = *(const float4*)&base[(size_t)(m0 + ar0 + 64) * 512 + kk + ak4];
      rb  = *(const float4*)&B[(size_t)(kn + bk) * 512 + n0 + bn4];
    }
#pragma unroll
    for (int k = 0; k < 16; ++k) {
      float4 a0 = *(float4*)&As[k * AS_STR + (ty << 3)];
      float4 a1 = *(float4*)&As[k * AS_STR + (ty << 3) + 4];
      float4 b  = *(float4*)&Bs[k * 64 + (tx << 2)];
      float av[8] = {a0.x, a0.y, a0.z, a0.w, a1.x, a1.y, a1.z, a1.w};
      float bv[4] = {b.x, b.y, b.z, b.w};
#pragma unroll
      for (int i = 0; i < 8; ++i)
#pragma unroll
        for (int j = 0; j < 4; ++j) acc[i][j] = fmaf(av[i], bv[j], acc[i][j]);
    }
  }
#pragma unroll
  for (int i = 0; i < 8; ++i) {
    float4 o = {acc[i][0], acc[i][1], acc[i][2], acc[i][3]};
    *(float4*)&C[(size_t)(m0 + (ty << 3) + i) * 512 + n0 + (tx << 2)] = o;
  }
}

// ============================================================================
// pass1: SINGLE Ht_C stream. Per row: dot with Qk -> logit -> e=exp(logit),
// accumulate e-weighted row in registers (flash-style, no max needed: logits
// ~N(0,1), exp cannot overflow fp32). Normalize by sum(e) at the end.
// ============================================================================
__global__ __launch_bounds__(256) void pass1_kernel(const float* __restrict__ HtC,
                                                    const int* __restrict__ caps,
                                                    const int* __restrict__ dists,
                                                    const float* __restrict__ Qkp,
                                                    const float* __restrict__ cap_emb,
                                                    const float* __restrict__ dist_emb,
                                                    float* __restrict__ Gw) {
  const int b = blockIdx.x;
  const int t = threadIdx.x;
  const int wv = t >> 6, ln = t & 63;
  __shared__ float qk[DH];
  __shared__ float capQ[11], distQ[3];
  __shared__ float capE[11], distE[3];
  __shared__ float ec[CC];
  __shared__ float accs[4][DH];
  __shared__ float lsum_s;
  if (t < 11) capE[t] = 0.f;
  if (t < 3) distE[t] = 0.f;
  // sum 4 split-K partials of Qk[b]
  {
    float q0 = 0.f, q1 = 0.f;
#pragma unroll
    for (int z = 0; z < 4; ++z) {
      q0 += Qkp[(size_t)z * NB * DH + (size_t)b * DH + t];
      q1 += Qkp[(size_t)z * NB * DH + (size_t)b * DH + 256 + t];
    }
    qk[t] = q0;
    qk[t + 256] = q1;
  }
  __syncthreads();
  // embedding-vector dots with Qk[b]
#pragma unroll
  for (int r = 0; r < 3; ++r) {
    int v = wv + (r << 2);
    if (v < 11) {
      float s = 0.f;
#pragma unroll
      for (int j = 0; j < 8; ++j) s = fmaf(cap_emb[v * DH + ln + (j << 6)], qk[ln + (j << 6)], s);
      s = wsum(s);
      if (ln == 0) capQ[v] = s;
    }
  }
  if (wv < 3) {
    float s = 0.f;
#pragma unroll
    for (int j = 0; j < 8; ++j) s = fmaf(dist_emb[wv * DH + ln + (j << 6)], qk[ln + (j << 6)], s);
    s = wsum(s);
    if (ln == 0) distQ[wv] = s;
  }
  __syncthreads();
  const float4* qk4 = (const float4*)qk;
  float4 q1 = qk4[ln];
  float4 q2 = qk4[64 + ln];
  const float* hb = HtC + (size_t)b * CC * DH;
  float a0 = 0.f, a1 = 0.f, a2 = 0.f, a3 = 0.f, a4 = 0.f, a5 = 0.f, a6 = 0.f, a7 = 0.f;
#pragma unroll 4
  for (int i = 0; i < 16; ++i) {
    int c = (wv << 4) + i;
    const float4* h4 = (const float4*)(hb + (size_t)c * DH);
    float4 h1 = h4[ln];
    float4 h2 = h4[64 + ln];
    float s = h1.x * q1.x + h1.y * q1.y + h1.z * q1.z + h1.w * q1.w +
              h2.x * q2.x + h2.y * q2.y + h2.z * q2.z + h2.w * q2.w;
    s = wsum(s);
    float logit = SCALE * (s + capQ[caps[b * CC + c]] + distQ[dists[b * CC + c]]);
    float e = __expf(logit);
    if (ln == 0) ec[c] = e;
    a0 = fmaf(e, h1.x, a0); a1 = fmaf(e, h1.y, a1);
    a2 = fmaf(e, h1.z, a2); a3 = fmaf(e, h1.w, a3);
    a4 = fmaf(e, h2.x, a4); a5 = fmaf(e, h2.y, a5);
    a6 = fmaf(e, h2.z, a6); a7 = fmaf(e, h2.w, a7);
  }
  // per-wave register accumulators -> LDS
  {
    int d0 = ln << 2;
    accs[wv][d0 + 0] = a0; accs[wv][d0 + 1] = a1;
    accs[wv][d0 + 2] = a2; accs[wv][d0 + 3] = a3;
    accs[wv][256 + d0 + 0] = a4; accs[wv][256 + d0 + 1] = a5;
    accs[wv][256 + d0 + 2] = a6; accs[wv][256 + d0 + 3] = a7;
  }
  __syncthreads();
  if (t < CC) {
    float e = ec[t];
    float l = wsum(e);
    if (t == 0) lsum_s = l;
    atomicAdd(&capE[caps[b * CC + t]], e);
    atomicAdd(&distE[dists[b * CC + t]], e);
  }
  __syncthreads();
  const float rinv = 1.0f / lsum_s;
#pragma unroll
  for (int dd = 0; dd < 2; ++dd) {
    int d = t + (dd << 8);
    float g = accs[0][d] + accs[1][d] + accs[2][d] + accs[3][d];
#pragma unroll
    for (int v = 0; v < 11; ++v) g = fmaf(capE[v], cap_emb[v * DH + d], g);
#pragma unroll
    for (int v = 0; v < 3; ++v) g = fmaf(distE[v], dist_emb[v * DH + d], g);
    Gw[(size_t)b * DH + d] = g * rinv;
  }
}

// ============================================================================
// pass2: u -> mask -> softmax -> out (single Ht_C stream; sums 2 gk partials)
// ============================================================================
__global__ __launch_bounds__(256) void pass2_kernel(const float* __restrict__ HtC,
                                                    const int* __restrict__ caps,
                                                    const int* __restrict__ dists,
                                                    const float* __restrict__ Gkp,
                                                    const float* __restrict__ cap_emb,
                                                    const float* __restrict__ dist_emb,
                                                    const int* __restrict__ need,
                                                    float* __restrict__ out) {
  const int b = blockIdx.x;
  const int t = threadIdx.x;
  const int wv = t >> 6, ln = t & 63;
  __shared__ float gk[DH];
  __shared__ float capG[11], distG[3];
  __shared__ float ulog[CC];
  {
    float g0 = Gkp[(size_t)b * DH + t] + Gkp[(size_t)NB * DH + (size_t)b * DH + t];
    float g1 = Gkp[(size_t)b * DH + 256 + t] + Gkp[(size_t)NB * DH + (size_t)b * DH + 256 + t];
    gk[t] = g0;
    gk[t + 256] = g1;
  }
  __syncthreads();
#pragma unroll
  for (int r = 0; r < 3; ++r) {
    int v = wv + (r << 2);
    if (v < 11) {
      float s = 0.f;
#pragma unroll
      for (int j = 0; j < 8; ++j) s = fmaf(cap_emb[v * DH + ln + (j << 6)], gk[ln + (j << 6)], s);
      s = wsum(s);
      if (ln == 0) capG[v] = s;
    }
  }
  if (wv < 3) {
    float s = 0.f;
#pragma unroll
    for (int j = 0; j < 8; ++j) s = fmaf(dist_emb[wv * DH + ln + (j << 6)], gk[ln + (j << 6)], s);
    s = wsum(s);
    if (ln == 0) distG[wv] = s;
  }
  __syncthreads();
  const float4* gk4 = (const float4*)gk;
  float4 q1 = gk4[ln];
  float4 q2 = gk4[64 + ln];
  const float* hb = HtC + (size_t)b * CC * DH;
#pragma unroll 4
  for (int i = 0; i < 16; ++i) {
    int c = (wv << 4) + i;
    const float4* h4 = (const float4*)(hb + (size_t)c * DH);
    float4 h1 = h4[ln];
    float4 h2 = h4[64 + ln];
    float s = h1.x * q1.x + h1.y * q1.y + h1.z * q1.z + h1.w * q1.w +
              h2.x * q2.x + h2.y * q2.y + h2.z * q2.z + h2.w * q2.w;
    s = wsum(s);
    if (ln == 0)
      ulog[c] = SCALE * (s + capG[caps[b * CC + c]] + distG[dists[b * CC + c]]);
  }
  __syncthreads();
  if (t < CC) {
    int nb = need[b];
    float x = ulog[t];
    if (caps[b * CC + t] < nb) x = -INFINITY;
    float m = x;
#pragma unroll
    for (int off = 32; off; off >>= 1) m = fmaxf(m, __shfl_xor(m, off, 64));
    float e = __expf(x - m);
    float ssum = wsum(e);
    out[(size_t)b * CC + t] = e / ssum;
  }
}

// ---------------- launch ----------------
extern "C" void kernel_launch(void* const* d_in, const int* in_sizes, int n_in,
                              void* d_out, int out_size, void* d_ws, size_t ws_size,
                              hipStream_t stream) {
  const float* HtC      = (const float*)d_in[0];
  const int* caps       = (const int*)d_in[1];
  const int* dists      = (const int*)d_in[2];
  const float* H_X      = (const float*)d_in[3];
  const float* Ht_S     = (const float*)d_in[4];
  const float* Eq_Q     = (const float*)d_in[5];
  const unsigned char* dbl = (const unsigned char*)d_in[6];
  const float* cap_emb  = (const float*)d_in[7];
  const float* dist_emb = (const float*)d_in[8];
  const float* W_q      = (const float*)d_in[9];
  const float* W_k      = (const float*)d_in[10];
  const float* W_v      = (const float*)d_in[11];
  float* out = (float*)d_out;

  float* ws     = (float*)d_ws;
  float* wsA    = ws;                        // [1536,512]     A = W_q^T @ W_k
  float* wsM    = wsA + 1536 * 512;          // [512,512]      M = W_v^T @ W_k
  float* wsQkp  = wsM + 512 * 512;           // [4][2048,512]  Qk split-K partials
  float* wsGw   = wsQkp + 4 * 2048 * 512;    // [2048,512]
  float* wsGkp  = wsGw + 2048 * 512;         // [2][2048,512]  gk split-K partials
  int* wsNeed   = (int*)(wsGkp + 2 * 2048 * 512);

  // wsA/wsM precompute (256 GEMM blocks) + need detection (block 256)
  pre_kernel<<<257, 128, 0, stream>>>(W_q, W_v, W_k, wsA, wsM, dbl, wsNeed);
  // Qk = ctx @ wsA, K=1536, split-K=4 partials
  gemm_nn2p<<<dim3(16, 8, 4), 256, 0, stream>>>(H_X, Ht_S, Eq_Q, wsA, wsQkp, 384);
  // logits -> softmax -> Gw in ONE Ht_C stream
  pass1_kernel<<<NB, 256, 0, stream>>>(HtC, caps, dists, wsQkp, cap_emb, dist_emb, wsGw);
  // gk = Gw @ wsM, K=512, split-K=2 partials
  gemm_nn2p<<<dim3(16, 8, 2), 256, 0, stream>>>(wsGw, wsGw, wsGw, wsM, wsGkp, 256);
  // u -> mask -> softmax -> out
  pass2_kernel<<<NB, 256, 0, stream>>>(HtC, caps, dists, wsGkp, cap_emb, dist_emb, wsNeed, out);
}

// Round 4
// 528.439 us; speedup vs baseline: 1.2776x; 1.0033x over previous
//
#include <hip/hip_runtime.h>
#include <math.h>

#define DH 512
#define CC 64
#define NB 2048
#define SCALE 0.044194173824159216f   // 1/sqrt(512)

// ---------------- wave helpers ----------------
__device__ __forceinline__ float wsum(float v) {
#pragma unroll
  for (int off = 32; off; off >>= 1) v += __shfl_xor(v, off, 64);
  return v;
}

// ============================================================================
// pre_kernel: blocks 0..255 compute wsA = W_q^T @ W_k (rows 0..1535) and
// wsM = W_v^T @ W_k (rows 1536..2047) with 64x64 tiles; block 256 does the
// bool-layout detection for `double` -> need[b] in {1,2}.
// ============================================================================
__global__ __launch_bounds__(128) void pre_kernel(const float* __restrict__ Wq,
                                                  const float* __restrict__ Wv,
                                                  const float* __restrict__ Wk,
                                                  float* __restrict__ Aout,
                                                  float* __restrict__ Mout,
                                                  const unsigned char* __restrict__ dbl,
                                                  int* __restrict__ need) {
  const int bx = blockIdx.x;
  const int t = threadIdx.x;
  if (bx == 256) {
    __shared__ int flagNZ, flagFP;
    if (t == 0) { flagNZ = 0; flagFP = 0; }
    __syncthreads();
    int nz = 0, fp = 0;
    for (int i = t; i < NB; i += 128) {
      if (i & 3) {
        unsigned char v = dbl[i];
        nz |= (v != 0);
        fp |= (v == 0x3f) | (v == 0x80);
      }
    }
    if (nz) atomicOr(&flagNZ, 1);
    if (fp) atomicOr(&flagFP, 1);
    __syncthreads();
    const int isFP = flagFP, isByte = flagNZ && !flagFP;
    for (int i = t; i < NB; i += 128) {
      int v;
      if (isFP)        v = (((const float*)dbl)[i] != 0.0f);
      else if (isByte) v = (dbl[i] != 0);
      else             v = (((const int*)dbl)[i] != 0);
      need[i] = v ? 2 : 1;
    }
    return;
  }
  __shared__ float As[16][64];
  __shared__ float Bs[16][64];
  const int mt = bx >> 3, nt = bx & 7;
  const int m0 = mt * 64, n0 = nt * 64;
  const bool isQ = (m0 < 1536);
  const float* Acol = isQ ? (Wq + m0) : (Wv + (m0 - 1536));
  const int lda = isQ ? 1536 : 512;
  float* Cout = isQ ? (Aout + (size_t)m0 * 512) : (Mout + (size_t)(m0 - 1536) * 512);
  const int lr = t >> 3;
  const int lc = (t & 7) << 3;
  const int tx = t & 15, ty = t >> 4;

  float4 ra0, ra1, rb0, rb1;
  ra0 = *(const float4*)&Acol[(size_t)lr * lda + lc];
  ra1 = *(const float4*)&Acol[(size_t)lr * lda + lc + 4];
  rb0 = *(const float4*)&Wk[(size_t)lr * 512 + n0 + lc];
  rb1 = *(const float4*)&Wk[(size_t)lr * 512 + n0 + lc + 4];
  float acc[8][4] = {};
  for (int k0 = 0; k0 < 512; k0 += 16) {
    __syncthreads();
    *(float4*)&As[lr][lc] = ra0;
    *(float4*)&As[lr][lc + 4] = ra1;
    *(float4*)&Bs[lr][lc] = rb0;
    *(float4*)&Bs[lr][lc + 4] = rb1;
    __syncthreads();
    if (k0 + 16 < 512) {
      const int kn = k0 + 16 + lr;
      ra0 = *(const float4*)&Acol[(size_t)kn * lda + lc];
      ra1 = *(const float4*)&Acol[(size_t)kn * lda + lc + 4];
      rb0 = *(const float4*)&Wk[(size_t)kn * 512 + n0 + lc];
      rb1 = *(const float4*)&Wk[(size_t)kn * 512 + n0 + lc + 4];
    }
#pragma unroll
    for (int k = 0; k < 16; ++k) {
      float4 a0 = *(float4*)&As[k][ty << 3];
      float4 a1 = *(float4*)&As[k][(ty << 3) + 4];
      float4 b  = *(float4*)&Bs[k][tx << 2];
      float av[8] = {a0.x, a0.y, a0.z, a0.w, a1.x, a1.y, a1.z, a1.w};
      float bv[4] = {b.x, b.y, b.z, b.w};
#pragma unroll
      for (int i = 0; i < 8; ++i)
#pragma unroll
        for (int j = 0; j < 4; ++j) acc[i][j] = fmaf(av[i], bv[j], acc[i][j]);
    }
  }
#pragma unroll
  for (int i = 0; i < 8; ++i) {
    float4 o = {acc[i][0], acc[i][1], acc[i][2], acc[i][3]};
    *(float4*)&Cout[(size_t)((ty << 3) + i) * 512 + n0 + (tx << 2)] = o;
  }
}

// ============================================================================
// gemm_nn2p: 128x64 tile, 8x4 micro, reg-prefetch, split-K to PARTIAL buffers
// ============================================================================
#define AS_STR 132

__global__ __launch_bounds__(256) void gemm_nn2p(const float* __restrict__ A0,
                                                 const float* __restrict__ A1,
                                                 const float* __restrict__ A2,
                                                 const float* __restrict__ B,
                                                 float* __restrict__ Cp,
                                                 int kchunk) {
  __shared__ float As[16 * AS_STR];
  __shared__ float Bs[16 * 64];
  const int t = threadIdx.x;
  const int m0 = blockIdx.x * 128, n0 = blockIdx.y * 64;
  const int kbeg = blockIdx.z * kchunk, kend = kbeg + kchunk;
  float* C = Cp + (size_t)blockIdx.z * (NB * DH);
  const int tx = t & 15, ty = t >> 4;
  const int ar0 = t >> 2;
  const int ak4 = (t & 3) << 2;
  const int bk = t >> 4, bn4 = (t & 15) << 2;

  float4 ra0, ra1, rb;
  {
    const float* base = (kbeg < 512) ? A0 : ((kbeg < 1024) ? A1 : A2);
    const int kk = kbeg & 511;
    ra0 = *(const float4*)&base[(size_t)(m0 + ar0) * 512 + kk + ak4];
    ra1 = *(const float4*)&base[(size_t)(m0 + ar0 + 64) * 512 + kk + ak4];
    rb  = *(const float4*)&B[(size_t)(kbeg + bk) * 512 + n0 + bn4];
  }
  float acc[8][4] = {};
  for (int k0 = kbeg; k0 < kend; k0 += 16) {
    __syncthreads();
    As[(ak4 + 0) * AS_STR + ar0] = ra0.x;
    As[(ak4 + 1) * AS_STR + ar0] = ra0.y;
    As[(ak4 + 2) * AS_STR + ar0] = ra0.z;
    As[(ak4 + 3) * AS_STR + ar0] = ra0.w;
    As[(ak4 + 0) * AS_STR + ar0 + 64] = ra1.x;
    As[(ak4 + 1) * AS_STR + ar0 + 64] = ra1.y;
    As[(ak4 + 2) * AS_STR + ar0 + 64] = ra1.z;
    As[(ak4 + 3) * AS_STR + ar0 + 64] = ra1.w;
    *(float4*)&Bs[bk * 64 + bn4] = rb;
    __syncthreads();
    if (k0 + 16 < kend) {
      const int kn = k0 + 16;
      const float* base = (kn < 512) ? A0 : ((kn < 1024) ? A1 : A2);
      const int kk = kn & 511;
      ra0 = *(const float4*)&base[(size_t)(m0 + ar0) * 512 + kk + ak4];
      ra1 = *(const float4*)&base[(size_t)(m0 + ar0 + 64) * 512 + kk + ak4];
      rb  = *(const float4*)&B[(size_t)(kn + bk) * 512 + n0 + bn4];
    }
#pragma unroll
    for (int k = 0; k < 16; ++k) {
      float4 a0 = *(float4*)&As[k * AS_STR + (ty << 3)];
      float4 a1 = *(float4*)&As[k * AS_STR + (ty << 3) + 4];
      float4 b  = *(float4*)&Bs[k * 64 + (tx << 2)];
      float av[8] = {a0.x, a0.y, a0.z, a0.w, a1.x, a1.y, a1.z, a1.w};
      float bv[4] = {b.x, b.y, b.z, b.w};
#pragma unroll
      for (int i = 0; i < 8; ++i)
#pragma unroll
        for (int j = 0; j < 4; ++j) acc[i][j] = fmaf(av[i], bv[j], acc[i][j]);
    }
  }
#pragma unroll
  for (int i = 0; i < 8; ++i) {
    float4 o = {acc[i][0], acc[i][1], acc[i][2], acc[i][3]};
    *(float4*)&C[(size_t)(m0 + (ty << 3) + i) * 512 + n0 + (tx << 2)] = o;
  }
}

// ============================================================================
// pass1: SINGLE Ht_C stream (ascending b). Flash-style exp accumulation.
// ============================================================================
__global__ __launch_bounds__(256) void pass1_kernel(const float* __restrict__ HtC,
                                                    const int* __restrict__ caps,
                                                    const int* __restrict__ dists,
                                                    const float* __restrict__ Qkp,
                                                    const float* __restrict__ cap_emb,
                                                    const float* __restrict__ dist_emb,
                                                    float* __restrict__ Gw) {
  const int b = blockIdx.x;
  const int t = threadIdx.x;
  const int wv = t >> 6, ln = t & 63;
  __shared__ float qk[DH];
  __shared__ float capQ[11], distQ[3];
  __shared__ float capE[11], distE[3];
  __shared__ float ec[CC];
  __shared__ float accs[4][DH];
  __shared__ float lsum_s;
  if (t < 11) capE[t] = 0.f;
  if (t < 3) distE[t] = 0.f;
  {
    float q0 = 0.f, q1 = 0.f;
#pragma unroll
    for (int z = 0; z < 4; ++z) {
      q0 += Qkp[(size_t)z * NB * DH + (size_t)b * DH + t];
      q1 += Qkp[(size_t)z * NB * DH + (size_t)b * DH + 256 + t];
    }
    qk[t] = q0;
    qk[t + 256] = q1;
  }
  __syncthreads();
#pragma unroll
  for (int r = 0; r < 3; ++r) {
    int v = wv + (r << 2);
    if (v < 11) {
      float s = 0.f;
#pragma unroll
      for (int j = 0; j < 8; ++j) s = fmaf(cap_emb[v * DH + ln + (j << 6)], qk[ln + (j << 6)], s);
      s = wsum(s);
      if (ln == 0) capQ[v] = s;
    }
  }
  if (wv < 3) {
    float s = 0.f;
#pragma unroll
    for (int j = 0; j < 8; ++j) s = fmaf(dist_emb[wv * DH + ln + (j << 6)], qk[ln + (j << 6)], s);
    s = wsum(s);
    if (ln == 0) distQ[wv] = s;
  }
  __syncthreads();
  const float4* qk4 = (const float4*)qk;
  float4 q1 = qk4[ln];
  float4 q2 = qk4[64 + ln];
  const float* hb = HtC + (size_t)b * CC * DH;
  float a0 = 0.f, a1 = 0.f, a2 = 0.f, a3 = 0.f, a4 = 0.f, a5 = 0.f, a6 = 0.f, a7 = 0.f;
#pragma unroll 4
  for (int i = 0; i < 16; ++i) {
    int c = (wv << 4) + i;
    const float4* h4 = (const float4*)(hb + (size_t)c * DH);
    float4 h1 = h4[ln];
    float4 h2 = h4[64 + ln];
    float s = h1.x * q1.x + h1.y * q1.y + h1.z * q1.z + h1.w * q1.w +
              h2.x * q2.x + h2.y * q2.y + h2.z * q2.z + h2.w * q2.w;
    s = wsum(s);
    float logit = SCALE * (s + capQ[caps[b * CC + c]] + distQ[dists[b * CC + c]]);
    float e = __expf(logit);
    if (ln == 0) ec[c] = e;
    a0 = fmaf(e, h1.x, a0); a1 = fmaf(e, h1.y, a1);
    a2 = fmaf(e, h1.z, a2); a3 = fmaf(e, h1.w, a3);
    a4 = fmaf(e, h2.x, a4); a5 = fmaf(e, h2.y, a5);
    a6 = fmaf(e, h2.z, a6); a7 = fmaf(e, h2.w, a7);
  }
  {
    int d0 = ln << 2;
    accs[wv][d0 + 0] = a0; accs[wv][d0 + 1] = a1;
    accs[wv][d0 + 2] = a2; accs[wv][d0 + 3] = a3;
    accs[wv][256 + d0 + 0] = a4; accs[wv][256 + d0 + 1] = a5;
    accs[wv][256 + d0 + 2] = a6; accs[wv][256 + d0 + 3] = a7;
  }
  __syncthreads();
  if (t < CC) {
    float e = ec[t];
    float l = wsum(e);
    if (t == 0) lsum_s = l;
    atomicAdd(&capE[caps[b * CC + t]], e);
    atomicAdd(&distE[dists[b * CC + t]], e);
  }
  __syncthreads();
  const float rinv = 1.0f / lsum_s;
#pragma unroll
  for (int dd = 0; dd < 2; ++dd) {
    int d = t + (dd << 8);
    float g = accs[0][d] + accs[1][d] + accs[2][d] + accs[3][d];
#pragma unroll
    for (int v = 0; v < 11; ++v) g = fmaf(capE[v], cap_emb[v * DH + d], g);
#pragma unroll
    for (int v = 0; v < 3; ++v) g = fmaf(distE[v], dist_emb[v * DH + d], g);
    Gw[(size_t)b * DH + d] = g * rinv;
  }
}

// ============================================================================
// pass2: DESCENDING b order — pass1 leaves the tail of Ht_C resident in the
// 256 MiB L3 (268 MB stream, ~MRU tail survives); reading in reverse turns
// this pass mostly into L3 hits instead of a second full HBM stream.
// ============================================================================
__global__ __launch_bounds__(256) void pass2_kernel(const float* __restrict__ HtC,
                                                    const int* __restrict__ caps,
                                                    const int* __restrict__ dists,
                                                    const float* __restrict__ Gkp,
                                                    const float* __restrict__ cap_emb,
                                                    const float* __restrict__ dist_emb,
                                                    const int* __restrict__ need,
                                                    float* __restrict__ out) {
  const int b = NB - 1 - blockIdx.x;   // scan reversal vs pass1
  const int t = threadIdx.x;
  const int wv = t >> 6, ln = t & 63;
  __shared__ float gk[DH];
  __shared__ float capG[11], distG[3];
  __shared__ float ulog[CC];
  {
    float g0 = Gkp[(size_t)b * DH + t] + Gkp[(size_t)NB * DH + (size_t)b * DH + t];
    float g1 = Gkp[(size_t)b * DH + 256 + t] + Gkp[(size_t)NB * DH + (size_t)b * DH + 256 + t];
    gk[t] = g0;
    gk[t + 256] = g1;
  }
  __syncthreads();
#pragma unroll
  for (int r = 0; r < 3; ++r) {
    int v = wv + (r << 2);
    if (v < 11) {
      float s = 0.f;
#pragma unroll
      for (int j = 0; j < 8; ++j) s = fmaf(cap_emb[v * DH + ln + (j << 6)], gk[ln + (j << 6)], s);
      s = wsum(s);
      if (ln == 0) capG[v] = s;
    }
  }
  if (wv < 3) {
    float s = 0.f;
#pragma unroll
    for (int j = 0; j < 8; ++j) s = fmaf(dist_emb[wv * DH + ln + (j << 6)], gk[ln + (j << 6)], s);
    s = wsum(s);
    if (ln == 0) distG[wv] = s;
  }
  __syncthreads();
  const float4* gk4 = (const float4*)gk;
  float4 q1 = gk4[ln];
  float4 q2 = gk4[64 + ln];
  const float* hb = HtC + (size_t)b * CC * DH;
#pragma unroll 4
  for (int i = 0; i < 16; ++i) {
    int c = (wv << 4) + i;
    const float4* h4 = (const float4*)(hb + (size_t)c * DH);
    float4 h1 = h4[ln];
    float4 h2 = h4[64 + ln];
    float s = h1.x * q1.x + h1.y * q1.y + h1.z * q1.z + h1.w * q1.w +
              h2.x * q2.x + h2.y * q2.y + h2.z * q2.z + h2.w * q2.w;
    s = wsum(s);
    if (ln == 0)
      ulog[c] = SCALE * (s + capG[caps[b * CC + c]] + distG[dists[b * CC + c]]);
  }
  __syncthreads();
  if (t < CC) {
    int nb = need[b];
    float x = ulog[t];
    if (caps[b * CC + t] < nb) x = -INFINITY;
    float m = x;
#pragma unroll
    for (int off = 32; off; off >>= 1) m = fmaxf(m, __shfl_xor(m, off, 64));
    float e = __expf(x - m);
    float ssum = wsum(e);
    out[(size_t)b * CC + t] = e / ssum;
  }
}

// ---------------- launch ----------------
extern "C" void kernel_launch(void* const* d_in, const int* in_sizes, int n_in,
                              void* d_out, int out_size, void* d_ws, size_t ws_size,
                              hipStream_t stream) {
  const float* HtC      = (const float*)d_in[0];
  const int* caps       = (const int*)d_in[1];
  const int* dists      = (const int*)d_in[2];
  const float* H_X      = (const float*)d_in[3];
  const float* Ht_S     = (const float*)d_in[4];
  const float* Eq_Q     = (const float*)d_in[5];
  const unsigned char* dbl = (const unsigned char*)d_in[6];
  const float* cap_emb  = (const float*)d_in[7];
  const float* dist_emb = (const float*)d_in[8];
  const float* W_q      = (const float*)d_in[9];
  const float* W_k      = (const float*)d_in[10];
  const float* W_v      = (const float*)d_in[11];
  float* out = (float*)d_out;

  float* ws     = (float*)d_ws;
  float* wsA    = ws;                        // [1536,512]     A = W_q^T @ W_k
  float* wsM    = wsA + 1536 * 512;          // [512,512]      M = W_v^T @ W_k
  float* wsQkp  = wsM + 512 * 512;           // [4][2048,512]  Qk split-K partials
  float* wsGw   = wsQkp + 4 * 2048 * 512;    // [2048,512]
  float* wsGkp  = wsGw + 2048 * 512;         // [2][2048,512]  gk split-K partials
  int* wsNeed   = (int*)(wsGkp + 2 * 2048 * 512);

  pre_kernel<<<257, 128, 0, stream>>>(W_q, W_v, W_k, wsA, wsM, dbl, wsNeed);
  gemm_nn2p<<<dim3(16, 8, 4), 256, 0, stream>>>(H_X, Ht_S, Eq_Q, wsA, wsQkp, 384);
  pass1_kernel<<<NB, 256, 0, stream>>>(HtC, caps, dists, wsQkp, cap_emb, dist_emb, wsGw);
  gemm_nn2p<<<dim3(16, 8, 2), 256, 0, stream>>>(wsGw, wsGw, wsGw, wsM, wsGkp, 256);
  pass2_kernel<<<NB, 256, 0, stream>>>(HtC, caps, dists, wsGkp, cap_emb, dist_emb, wsNeed, out);
}